// Round 18
// baseline (97.188 us; speedup 1.0000x reference)
//
#include <hip/hip_runtime.h>

typedef _Float16 f16x8 __attribute__((ext_vector_type(8)));
typedef float    f32x4 __attribute__((ext_vector_type(4)));
typedef float    f32x16 __attribute__((ext_vector_type(16)));
typedef unsigned int u32;

#define N_CTX 16384
#define N_Q   4096
#define DIM   100
#define THR   5.7708f            // 4 nats in log2 units
#define LOG2E 1.4426950408889634f
#define LN2   0.6931471805599453f

union FragU { unsigned int u[4]; f16x8 v; };

#if __has_builtin(__builtin_amdgcn_exp2f)
#define EXP2(x) __builtin_amdgcn_exp2f(x)
#else
#define EXP2(x) exp2f(x)
#endif

#define MFMA32(a, b, c) __builtin_amdgcn_mfma_f32_32x32x16_f16((a), (b), (c), 0, 0, 0)
#define GLOAD_LDS(g, l) __builtin_amdgcn_global_load_lds( \
    (const __attribute__((address_space(1))) u32*)(const void*)(g), \
    (__attribute__((address_space(3))) u32*)(void*)(l), 16, 0, 0)

// ---------------- fused prep ----------------
// blocks 0..63   : Q pass (unchanged) — qTS + log2e-scaled j-permuted qbS + t.
// blocks 64..191 : ctx pass — cbH + a, 128 rows/block (tid<128).
__global__ void prep_all(const float* __restrict__ q, const float* __restrict__ ctx,
                         const float* __restrict__ ker,
                         unsigned short* __restrict__ qbS, unsigned short* __restrict__ qTS,
                         unsigned short* __restrict__ cbH, float* __restrict__ a) {
    int b = blockIdx.x;
    int tid = threadIdx.x;
    if (b < 64) {
        __shared__ _Float16 ldsT[100][64];
        __shared__ float tL[64];
        int j0 = b * 64;
        int r = tid >> 2, c = tid & 3;
        const float* row = q + (size_t)(j0 + r) * DIM + c * 25;
        float part = 0.f;
        #pragma unroll
        for (int k = 0; k < 25; ++k) {
            float v = row[k];
            ldsT[c * 25 + k][r] = (_Float16)v;
            part += v * ker[100 + c * 25 + k];
        }
        part += __shfl_xor(part, 1, 64);
        part += __shfl_xor(part, 2, 64);
        if (c == 0) tL[r] = part * LOG2E;
        __syncthreads();

        #pragma unroll
        for (int k = 0; k < 4; ++k) {
            int ci = tid + k * 256;
            int jb = ci >> 9;
            int rem = ci & 511;
            int dt = rem >> 7, rem2 = rem & 127;
            int o = rem2 >> 5, rr = rem2 & 31;
            int d = dt * 32 + rr;
            f16x8 v;
            #pragma unroll
            for (int e = 0; e < 8; ++e) {
                int jl = jb * 32 + 8 * o + e;
                v[e] = (d < DIM) ? ldsT[d][jl] : (d == DIM ? (_Float16)1.f : (_Float16)0.f);
            }
            char* dst = (char*)qTS + (size_t)((j0 >> 5) + jb) * 8192
                        + dt * 2048 + o * 512 + rr * 16;
            *reinterpret_cast<f16x8*>(dst) = v;
        }

        #pragma unroll
        for (int k = 0; k < 4; ++k) {
            int ci = tid + k * 256;
            int jl = ci & 63;
            int o  = ci >> 6;
            int j5 = jl & 31;
            int g = j5 >> 2, gm = g & 3;
            if (gm == 1 || gm == 2) g ^= 3;          // perm: swap groups 1<->2, 5<->6
            int slot = (g << 2) | (j5 & 3);
            int img  = (j0 >> 5) + (jl >> 5);
            f16x8 h;
            #pragma unroll
            for (int e = 0; e < 8; ++e) {
                int d = 8 * o + e;
                float v = (d < DIM) ? (float)ldsT[d][jl] * LOG2E
                                    : (d == DIM ? tL[jl] : 0.f);
                h[e] = (_Float16)v;
            }
            *reinterpret_cast<f16x8*>((char*)qbS + (size_t)img * 8192 + o * 512 + slot * 16) = h;
        }
    } else {
        if (tid >= 128) return;
        int i = (b - 64) * 128 + tid;
        const float* row = ctx + (size_t)i * DIM;
        float buf[100];
        float acc = 0.f;
        #pragma unroll
        for (int d4 = 0; d4 < 25; ++d4) {
            #pragma unroll
            for (int e = 0; e < 4; ++e) {
                float v = row[4 * d4 + e];
                buf[4 * d4 + e] = v;
                acc += v * ker[4 * d4 + e];
            }
        }
        a[i] = acc;
        unsigned short* orow = cbH + (size_t)i * 128;
        #pragma unroll
        for (int c = 0; c < 16; ++c) {
            f16x8 h;
            #pragma unroll
            for (int e = 0; e < 8; ++e) {
                int d = 8 * c + e;
                float v = (d < DIM) ? buf[d] * ker[200 + d] : (d == DIM ? 1.f : 0.f);
                h[e] = (_Float16)v;
            }
            *reinterpret_cast<f16x8*>(orow + 8 * c) = h;
        }
    }
}

// ---------------- main fused attention (unchanged from rounds 14-17) ----------------
__global__ __launch_bounds__(256, 4) void attn_main(
    const unsigned short* __restrict__ qbS, const unsigned short* __restrict__ qTS,
    const unsigned short* __restrict__ cbH,
    _Float16* __restrict__ Ub, float* __restrict__ mb,
    float* __restrict__ lb, float* __restrict__ mtb)
{
    __shared__ __align__(16) char stageMem[2][16384];

    const int tid  = threadIdx.x;
    const int w    = tid >> 6;
    const int lane = tid & 63;
    const int hi   = lane >> 5;
    const int c31  = lane & 31;
    const int it   = blockIdx.x;
    const int js   = blockIdx.y;
    const int JS   = gridDim.y;
    const int R    = (N_Q / 32) / JS;
    const int iw0  = it * 128 + w * 32;

    f16x8 cbF[7];
    {
        const unsigned short* crow = cbH + (size_t)(iw0 + c31) * 128 + 8 * hi;
        #pragma unroll
        for (int kk = 0; kk < 7; ++kk)
            cbF[kk] = *reinterpret_cast<const f16x8*>(crow + kk * 16);
    }

    f32x16 U0 = {}, U1 = {}, U2 = {}, U3 = {};
    float m = -INFINITY, mtrue = -INFINITY;    // in log2 units

    const int bb0 = js * R;
    const int seg = w * 2;
    const int l16 = lane * 16;

    auto stage_fn = [&](int buf, int bb) {
        const char* gq = (const char*)qbS + (size_t)bb * 8192;
        const char* gt = (const char*)qTS + (size_t)bb * 8192;
        char* lq = stageMem[buf];
        #pragma unroll
        for (int k = 0; k < 2; ++k)
            GLOAD_LDS(gq + (seg + k) * 1024 + l16, lq + (seg + k) * 1024);
        #pragma unroll
        for (int k = 0; k < 2; ++k)
            GLOAD_LDS(gt + (seg + k) * 1024 + l16, lq + 8192 + (seg + k) * 1024);
    };

    stage_fn(0, bb0);
    __syncthreads();
    int cur = 0;

    for (int r = 0; r < R; ++r) {
        if (r + 1 < R) stage_fn(cur ^ 1, bb0 + r + 1);

        const char* qbL = stageMem[cur];
        const char* qTL = stageMem[cur] + 8192;

        f32x16 sacc = {};
        __builtin_amdgcn_s_setprio(1);
        #pragma unroll
        for (int kk = 0; kk < 7; ++kk) {
            f16x8 aq = *reinterpret_cast<const f16x8*>(qbL + kk * 1024 + l16);
            sacc = MFMA32(aq, cbF[kk], sacc);
        }
        __builtin_amdgcn_s_setprio(0);

        float sc[16];
        #pragma unroll
        for (int q16 = 0; q16 < 16; ++q16) sc[q16] = sacc[q16];

        float x0 = fmaxf(fmaxf(sc[0],  sc[1]),  sc[2]);
        float x1 = fmaxf(fmaxf(sc[3],  sc[4]),  sc[5]);
        float x2 = fmaxf(fmaxf(sc[6],  sc[7]),  sc[8]);
        float x3 = fmaxf(fmaxf(sc[9],  sc[10]), sc[11]);
        float x4 = fmaxf(fmaxf(sc[12], sc[13]), sc[14]);
        float tm = fmaxf(fmaxf(fmaxf(x0, x1), x2), fmaxf(fmaxf(x3, x4), sc[15]));
        mtrue = fmaxf(mtrue, tm);

        if (__any(tm > m + THR)) {
            float tmf = fmaxf(tm, __shfl_xor(tm, 32, 64));
            float mn = fmaxf(m, tmf);
            float scale = EXP2(m - mn);
            U0 *= scale; U1 *= scale; U2 *= scale; U3 *= scale;
            m = mn;
        }

        #pragma unroll
        for (int q16 = 0; q16 < 16; ++q16) sc[q16] = EXP2(sc[q16] - m);

        FragU f0, f1;
        #pragma unroll
        for (int e2 = 0; e2 < 4; ++e2) {
            auto p0 = __builtin_amdgcn_cvt_pkrtz(sc[2 * e2],     sc[2 * e2 + 1]);
            auto p1 = __builtin_amdgcn_cvt_pkrtz(sc[8 + 2 * e2], sc[8 + 2 * e2 + 1]);
            f0.u[e2] = __builtin_bit_cast(unsigned int, p0);
            f1.u[e2] = __builtin_bit_cast(unsigned int, p1);
        }

        __builtin_amdgcn_s_setprio(1);
        {
            f16x8 a0 = *reinterpret_cast<const f16x8*>(qTL + l16);
            f16x8 a1 = *reinterpret_cast<const f16x8*>(qTL + 1024 + l16);
            U0 = MFMA32(a0, f0.v, U0);
            U0 = MFMA32(a1, f1.v, U0);
        }
        {
            f16x8 a0 = *reinterpret_cast<const f16x8*>(qTL + 2048 + l16);
            f16x8 a1 = *reinterpret_cast<const f16x8*>(qTL + 3072 + l16);
            U1 = MFMA32(a0, f0.v, U1);
            U1 = MFMA32(a1, f1.v, U1);
        }
        {
            f16x8 a0 = *reinterpret_cast<const f16x8*>(qTL + 4096 + l16);
            f16x8 a1 = *reinterpret_cast<const f16x8*>(qTL + 5120 + l16);
            U2 = MFMA32(a0, f0.v, U2);
            U2 = MFMA32(a1, f1.v, U2);
        }
        {
            f16x8 a0 = *reinterpret_cast<const f16x8*>(qTL + 6144 + l16);
            f16x8 a1 = *reinterpret_cast<const f16x8*>(qTL + 7168 + l16);
            U3 = MFMA32(a0, f0.v, U3);
            U3 = MFMA32(a1, f1.v, U3);
        }
        __builtin_amdgcn_s_setprio(0);

        __syncthreads();
        cur ^= 1;
    }

    mtrue = fmaxf(mtrue, __shfl_xor(mtrue, 32, 64));
    float ltmp = __shfl_xor(U3[0], 32, 64);
    float lfull = hi ? U3[0] : ltmp;

    int irow = iw0 + c31;
    if (hi == 0) {
        mb [(size_t)js * N_CTX + irow] = m;                 // log2 domain
        lb [(size_t)js * N_CTX + irow] = lfull;
        mtb[(size_t)js * N_CTX + irow] = mtrue * LN2;       // natural domain
    }
    _Float16* ub = Ub + (((size_t)js * 128 + it) * DIM) * 128 + w * 32 + c31;
    #pragma unroll
    for (int r = 0; r < 16; ++r) {
        int dl = (r & 3) + 8 * (r >> 2) + 4 * hi;
        ub[(size_t)dl * 128]        = (_Float16)U0[r];
        ub[(size_t)(32 + dl) * 128] = (_Float16)U1[r];
        ub[(size_t)(64 + dl) * 128] = (_Float16)U2[r];
        if (96 + dl < DIM) ub[(size_t)(96 + dl) * 128] = (_Float16)U3[r];
    }
}

// ---------------- tail kernels ----------------

// 64 blocks; computes mfull inline (a + max_js mtb), block-LOCAL max M_b,
// raw h-numerator partials + z partials under M_b.
template<int JS>
__global__ void kernel_h(const float* __restrict__ a, const float* __restrict__ mtb,
                         const float* __restrict__ ctx,
                         float* __restrict__ hp, float* __restrict__ zp,
                         float* __restrict__ Mp) {
    __shared__ float mfL[256];
    __shared__ float red[256];
    __shared__ float smh[8][104];
    __shared__ float smz[8];
    int t = threadIdx.x;
    int i0 = blockIdx.x * 256;
    int row = i0 + t;
    float mt = -INFINITY;
    #pragma unroll
    for (int js = 0; js < JS; ++js) mt = fmaxf(mt, mtb[(size_t)js * N_CTX + row]);
    float mf = a[row] + mt;
    mfL[t] = mf;
    red[t] = mf;
    __syncthreads();
    for (int s = 128; s > 0; s >>= 1) { if (t < s) red[t] = fmaxf(red[t], red[t + s]); __syncthreads(); }
    float Mb = red[0];
    if (t == 0) Mp[blockIdx.x] = Mb;

    int rr = t >> 5, d32 = t & 31;
    float a0 = 0.f, a1 = 0.f, a2 = 0.f, a3 = 0.f, wz = 0.f;
    for (int g = 0; g < 32; ++g) {
        int r = g * 8 + rr;
        float bw = __expf(mfL[r] - Mb);
        const float* cr = ctx + (size_t)(i0 + r) * DIM;
        a0 += bw * cr[d32];
        a1 += bw * cr[d32 + 32];
        a2 += bw * cr[d32 + 64];
        if (d32 < 4) a3 += bw * cr[d32 + 96];
        wz += bw;
    }
    smh[rr][d32]      = a0;
    smh[rr][d32 + 32] = a1;
    smh[rr][d32 + 64] = a2;
    if (d32 < 4) smh[rr][d32 + 96] = a3;
    if (d32 == 0) smz[rr] = wz;
    __syncthreads();
    if (t < DIM) {
        float s = 0.f;
        #pragma unroll
        for (int g = 0; g < 8; ++g) s += smh[g][t];
        hp[blockIdx.x * DIM + t] = s;
    }
    if (t == 0) {
        float z = 0.f;
        #pragma unroll
        for (int g = 0; g < 8; ++g) z += smz[g];
        zp[blockIdx.x] = z;
    }
}

// ---------------- combine: 1024 blocks x 16 rows ----------------
template<int JS>
__global__ __launch_bounds__(256, 4) void combine(
    const _Float16* __restrict__ Ub, const float* __restrict__ mb,
    const float* __restrict__ lb, const float* __restrict__ hp,
    const float* __restrict__ zp, const float* __restrict__ Mp,
    const float* __restrict__ ctx, float* __restrict__ G)
{
    __shared__ __align__(16) float ctxL[16][100];
    __shared__ __align__(16) float uaL[16][100];
    __shared__ __align__(16) float hL[100];

    const int b   = blockIdx.x;
    const int tid = threadIdx.x;

    for (int idx = tid; idx < 400; idx += 256) {
        int r = idx / 25, c4 = idx - r * 25;
        *reinterpret_cast<f32x4*>(&ctxL[r][c4 * 4]) =
            *reinterpret_cast<const f32x4*>(ctx + (size_t)(b * 16 + r) * DIM + c4 * 4);
    }
    if (tid < DIM) {
        float M = -INFINITY;
        #pragma unroll 8
        for (int bb = 0; bb < 64; ++bb) M = fmaxf(M, Mp[bb]);
        float s = 0.f, z = 0.f;
        #pragma unroll 4
        for (int bb = 0; bb < 64; ++bb) {
            float wbb = __expf(Mp[bb] - M);
            s += hp[bb * DIM + tid] * wbb;
            z += zp[bb] * wbb;
        }
        hL[tid] = s / z;
    }
    __syncthreads();

    {
        int i16 = tid & 15, seg = tid >> 4;          // 16 segs
        int row = b * 16 + i16;
        int iblk = row >> 7, il = row & 127;
        float mw[JS];
        float M = -INFINITY;
        #pragma unroll
        for (int js = 0; js < JS; ++js) {
            mw[js] = mb[(size_t)js * N_CTX + row];
            M = fmaxf(M, mw[js]);
        }
        float ew[JS];
        float L = 0.f;
        #pragma unroll
        for (int js = 0; js < JS; ++js) {
            ew[js] = EXP2(mw[js] - M);               // mb is log2-domain
            L += lb[(size_t)js * N_CTX + row] * ew[js];
        }
        float invL = 1.f / L;
        for (int d = seg; d < DIM; d += 16) {
            float u = 0.f;
            #pragma unroll
            for (int js = 0; js < JS; ++js)
                u += (float)Ub[(((size_t)js * 128 + iblk) * DIM + d) * 128 + il] * ew[js];
            uaL[i16][d] = u * invL;
        }
    }
    __syncthreads();

    float* gOut = G + (size_t)b * 16 * 400;
    for (int idx = tid; idx < 1600; idx += 256) {
        int r = idx / 100, c4 = idx - r * 100;
        int sel = c4 / 25, d4 = (c4 - sel * 25) * 4;
        f32x4 cv = *reinterpret_cast<const f32x4*>(&ctxL[r][d4]);
        f32x4 out;
        if (sel == 0)      out = cv;
        else if (sel == 1) out = *reinterpret_cast<const f32x4*>(&uaL[r][d4]);
        else if (sel == 2) out = *reinterpret_cast<const f32x4*>(&uaL[r][d4]) * cv;
        else               out = cv * *reinterpret_cast<const f32x4*>(&hL[d4]);
        *reinterpret_cast<f32x4*>(gOut + (size_t)r * 400 + c4 * 4) = out;
    }
}

// ---------------- launcher ----------------
extern "C" void kernel_launch(void* const* d_in, const int* in_sizes, int n_in,
                              void* d_out, int out_size, void* d_ws, size_t ws_size,
                              hipStream_t stream) {
    const float* ctx = (const float*)d_in[0];
    const float* q   = (const float*)d_in[1];
    const float* ker = (const float*)d_in[2];
    float* G = (float*)d_out;

    char* ws = (char*)d_ws;
    unsigned short* qbS   = (unsigned short*)(ws);                 // 1,048,576
    unsigned short* qTS   = (unsigned short*)(ws + 1048576);       // 1,048,576
    unsigned short* cbH   = (unsigned short*)(ws + 2097152);       // 4,194,304
    float*          a     = (float*)(ws + 6291456);                // 65,536
    float*          hp    = (float*)(ws + 6356992);                // 25,600
    float*          zp    = (float*)(ws + 6382592);                // 256
    float*          Mp    = (float*)(ws + 6382848);                // 256
    const size_t fixed = 6554112;

    int JS = 8;
    if (fixed + 8ull * 3473408ull > ws_size) JS = 4;
    if (fixed + 4ull * 3473408ull > ws_size) JS = 2;

    _Float16* Ub  = (_Float16*)(ws + fixed);
    size_t ubB    = (size_t)JS * 3276800ull;
    float*    mb  = (float*)(ws + fixed + ubB);
    float*    lb  = (float*)(ws + fixed + ubB + (size_t)JS * 65536ull);
    float*    mtb = (float*)(ws + fixed + ubB + (size_t)JS * 131072ull);

    prep_all<<<dim3(192), dim3(256), 0, stream>>>(q, ctx, ker, qbS, qTS, cbH, a);
    attn_main<<<dim3(128, JS), dim3(256), 0, stream>>>(qbS, qTS, cbH, Ub, mb, lb, mtb);

    if (JS == 8) {
        kernel_h<8><<<dim3(64), dim3(256), 0, stream>>>(a, mtb, ctx, hp, zp, Mp);
        combine<8><<<dim3(1024), dim3(256), 0, stream>>>(Ub, mb, lb, hp, zp, Mp, ctx, G);
    } else if (JS == 4) {
        kernel_h<4><<<dim3(64), dim3(256), 0, stream>>>(a, mtb, ctx, hp, zp, Mp);
        combine<4><<<dim3(1024), dim3(256), 0, stream>>>(Ub, mb, lb, hp, zp, Mp, ctx, G);
    } else {
        kernel_h<2><<<dim3(64), dim3(256), 0, stream>>>(a, mtb, ctx, hp, zp, Mp);
        combine<2><<<dim3(1024), dim3(256), 0, stream>>>(Ub, mb, lb, hp, zp, Mp, ctx, G);
    }
}

// Round 19
// 89.233 us; speedup vs baseline: 1.0892x; 1.0892x over previous
//
#include <hip/hip_runtime.h>

typedef _Float16 f16x8 __attribute__((ext_vector_type(8)));
typedef float    f32x4 __attribute__((ext_vector_type(4)));
typedef float    f32x16 __attribute__((ext_vector_type(16)));
typedef unsigned int u32;

#define N_CTX 16384
#define N_Q   4096
#define DIM   100
#define THR   5.7708f            // 4 nats in log2 units
#define LOG2E 1.4426950408889634f
#define LN2   0.6931471805599453f

union FragU { unsigned int u[4]; f16x8 v; };

#if __has_builtin(__builtin_amdgcn_exp2f)
#define EXP2(x) __builtin_amdgcn_exp2f(x)
#else
#define EXP2(x) exp2f(x)
#endif

#define MFMA32(a, b, c) __builtin_amdgcn_mfma_f32_32x32x16_f16((a), (b), (c), 0, 0, 0)
#define GLOAD_LDS(g, l) __builtin_amdgcn_global_load_lds( \
    (const __attribute__((address_space(1))) u32*)(const void*)(g), \
    (__attribute__((address_space(3))) u32*)(void*)(l), 16, 0, 0)

// ---------------- fused prep (round-16 configuration) ----------------
__global__ void prep_all(const float* __restrict__ q, const float* __restrict__ ctx,
                         const float* __restrict__ ker,
                         unsigned short* __restrict__ qbS, unsigned short* __restrict__ qTS,
                         unsigned short* __restrict__ cbH, float* __restrict__ a) {
    int b = blockIdx.x;
    int tid = threadIdx.x;
    if (b < 64) {
        __shared__ _Float16 ldsT[100][64];
        __shared__ float tL[64];
        int j0 = b * 64;
        int r = tid >> 2, c = tid & 3;
        const float* row = q + (size_t)(j0 + r) * DIM + c * 25;
        float part = 0.f;
        #pragma unroll
        for (int k = 0; k < 25; ++k) {
            float v = row[k];
            ldsT[c * 25 + k][r] = (_Float16)v;
            part += v * ker[100 + c * 25 + k];
        }
        part += __shfl_xor(part, 1, 64);
        part += __shfl_xor(part, 2, 64);
        if (c == 0) tL[r] = part * LOG2E;
        __syncthreads();

        #pragma unroll
        for (int k = 0; k < 4; ++k) {
            int ci = tid + k * 256;
            int jb = ci >> 9;
            int rem = ci & 511;
            int dt = rem >> 7, rem2 = rem & 127;
            int o = rem2 >> 5, rr = rem2 & 31;
            int d = dt * 32 + rr;
            f16x8 v;
            #pragma unroll
            for (int e = 0; e < 8; ++e) {
                int jl = jb * 32 + 8 * o + e;
                v[e] = (d < DIM) ? ldsT[d][jl] : (d == DIM ? (_Float16)1.f : (_Float16)0.f);
            }
            char* dst = (char*)qTS + (size_t)((j0 >> 5) + jb) * 8192
                        + dt * 2048 + o * 512 + rr * 16;
            *reinterpret_cast<f16x8*>(dst) = v;
        }

        #pragma unroll
        for (int k = 0; k < 4; ++k) {
            int ci = tid + k * 256;
            int jl = ci & 63;
            int o  = ci >> 6;
            int j5 = jl & 31;
            int g = j5 >> 2, gm = g & 3;
            if (gm == 1 || gm == 2) g ^= 3;          // perm: swap groups 1<->2, 5<->6
            int slot = (g << 2) | (j5 & 3);
            int img  = (j0 >> 5) + (jl >> 5);
            f16x8 h;
            #pragma unroll
            for (int e = 0; e < 8; ++e) {
                int d = 8 * o + e;
                float v = (d < DIM) ? (float)ldsT[d][jl] * LOG2E
                                    : (d == DIM ? tL[jl] : 0.f);
                h[e] = (_Float16)v;
            }
            *reinterpret_cast<f16x8*>((char*)qbS + (size_t)img * 8192 + o * 512 + slot * 16) = h;
        }
    } else {
        int i = (b - 64) * 256 + tid;
        const float* row = ctx + (size_t)i * DIM;
        float buf[100];
        float acc = 0.f;
        #pragma unroll
        for (int d4 = 0; d4 < 25; ++d4) {
            #pragma unroll
            for (int e = 0; e < 4; ++e) {
                float v = row[4 * d4 + e];
                buf[4 * d4 + e] = v;
                acc += v * ker[4 * d4 + e];
            }
        }
        a[i] = acc;
        unsigned short* orow = cbH + (size_t)i * 128;
        #pragma unroll
        for (int c = 0; c < 16; ++c) {
            f16x8 h;
            #pragma unroll
            for (int e = 0; e < 8; ++e) {
                int d = 8 * c + e;
                float v = (d < DIM) ? buf[d] * ker[200 + d] : (d == DIM ? 1.f : 0.f);
                h[e] = (_Float16)v;
            }
            *reinterpret_cast<f16x8*>(orow + 8 * c) = h;
        }
    }
}

// ---------------- main fused attention (rounds 14-16, structural floor) ----------------
__global__ __launch_bounds__(256, 4) void attn_main(
    const unsigned short* __restrict__ qbS, const unsigned short* __restrict__ qTS,
    const unsigned short* __restrict__ cbH,
    _Float16* __restrict__ Ub, float* __restrict__ mb,
    float* __restrict__ lb, float* __restrict__ mtb)
{
    __shared__ __align__(16) char stageMem[2][16384];

    const int tid  = threadIdx.x;
    const int w    = tid >> 6;
    const int lane = tid & 63;
    const int hi   = lane >> 5;
    const int c31  = lane & 31;
    const int it   = blockIdx.x;
    const int js   = blockIdx.y;
    const int JS   = gridDim.y;
    const int R    = (N_Q / 32) / JS;
    const int iw0  = it * 128 + w * 32;

    f16x8 cbF[7];
    {
        const unsigned short* crow = cbH + (size_t)(iw0 + c31) * 128 + 8 * hi;
        #pragma unroll
        for (int kk = 0; kk < 7; ++kk)
            cbF[kk] = *reinterpret_cast<const f16x8*>(crow + kk * 16);
    }

    f32x16 U0 = {}, U1 = {}, U2 = {}, U3 = {};
    float m = -INFINITY, mtrue = -INFINITY;    // in log2 units

    const int bb0 = js * R;
    const int seg = w * 2;
    const int l16 = lane * 16;

    auto stage_fn = [&](int buf, int bb) {
        const char* gq = (const char*)qbS + (size_t)bb * 8192;
        const char* gt = (const char*)qTS + (size_t)bb * 8192;
        char* lq = stageMem[buf];
        #pragma unroll
        for (int k = 0; k < 2; ++k)
            GLOAD_LDS(gq + (seg + k) * 1024 + l16, lq + (seg + k) * 1024);
        #pragma unroll
        for (int k = 0; k < 2; ++k)
            GLOAD_LDS(gt + (seg + k) * 1024 + l16, lq + 8192 + (seg + k) * 1024);
    };

    stage_fn(0, bb0);
    __syncthreads();
    int cur = 0;

    for (int r = 0; r < R; ++r) {
        if (r + 1 < R) stage_fn(cur ^ 1, bb0 + r + 1);

        const char* qbL = stageMem[cur];
        const char* qTL = stageMem[cur] + 8192;

        f32x16 sacc = {};
        __builtin_amdgcn_s_setprio(1);
        #pragma unroll
        for (int kk = 0; kk < 7; ++kk) {
            f16x8 aq = *reinterpret_cast<const f16x8*>(qbL + kk * 1024 + l16);
            sacc = MFMA32(aq, cbF[kk], sacc);
        }
        __builtin_amdgcn_s_setprio(0);

        float sc[16];
        #pragma unroll
        for (int q16 = 0; q16 < 16; ++q16) sc[q16] = sacc[q16];

        float x0 = fmaxf(fmaxf(sc[0],  sc[1]),  sc[2]);
        float x1 = fmaxf(fmaxf(sc[3],  sc[4]),  sc[5]);
        float x2 = fmaxf(fmaxf(sc[6],  sc[7]),  sc[8]);
        float x3 = fmaxf(fmaxf(sc[9],  sc[10]), sc[11]);
        float x4 = fmaxf(fmaxf(sc[12], sc[13]), sc[14]);
        float tm = fmaxf(fmaxf(fmaxf(x0, x1), x2), fmaxf(fmaxf(x3, x4), sc[15]));
        mtrue = fmaxf(mtrue, tm);

        if (__any(tm > m + THR)) {
            float tmf = fmaxf(tm, __shfl_xor(tm, 32, 64));
            float mn = fmaxf(m, tmf);
            float scale = EXP2(m - mn);
            U0 *= scale; U1 *= scale; U2 *= scale; U3 *= scale;
            m = mn;
        }

        #pragma unroll
        for (int q16 = 0; q16 < 16; ++q16) sc[q16] = EXP2(sc[q16] - m);

        FragU f0, f1;
        #pragma unroll
        for (int e2 = 0; e2 < 4; ++e2) {
            auto p0 = __builtin_amdgcn_cvt_pkrtz(sc[2 * e2],     sc[2 * e2 + 1]);
            auto p1 = __builtin_amdgcn_cvt_pkrtz(sc[8 + 2 * e2], sc[8 + 2 * e2 + 1]);
            f0.u[e2] = __builtin_bit_cast(unsigned int, p0);
            f1.u[e2] = __builtin_bit_cast(unsigned int, p1);
        }

        __builtin_amdgcn_s_setprio(1);
        {
            f16x8 a0 = *reinterpret_cast<const f16x8*>(qTL + l16);
            f16x8 a1 = *reinterpret_cast<const f16x8*>(qTL + 1024 + l16);
            U0 = MFMA32(a0, f0.v, U0);
            U0 = MFMA32(a1, f1.v, U0);
        }
        {
            f16x8 a0 = *reinterpret_cast<const f16x8*>(qTL + 2048 + l16);
            f16x8 a1 = *reinterpret_cast<const f16x8*>(qTL + 3072 + l16);
            U1 = MFMA32(a0, f0.v, U1);
            U1 = MFMA32(a1, f1.v, U1);
        }
        {
            f16x8 a0 = *reinterpret_cast<const f16x8*>(qTL + 4096 + l16);
            f16x8 a1 = *reinterpret_cast<const f16x8*>(qTL + 5120 + l16);
            U2 = MFMA32(a0, f0.v, U2);
            U2 = MFMA32(a1, f1.v, U2);
        }
        {
            f16x8 a0 = *reinterpret_cast<const f16x8*>(qTL + 6144 + l16);
            f16x8 a1 = *reinterpret_cast<const f16x8*>(qTL + 7168 + l16);
            U3 = MFMA32(a0, f0.v, U3);
            U3 = MFMA32(a1, f1.v, U3);
        }
        __builtin_amdgcn_s_setprio(0);

        __syncthreads();
        cur ^= 1;
    }

    mtrue = fmaxf(mtrue, __shfl_xor(mtrue, 32, 64));
    float ltmp = __shfl_xor(U3[0], 32, 64);
    float lfull = hi ? U3[0] : ltmp;

    int irow = iw0 + c31;
    if (hi == 0) {
        mb [(size_t)js * N_CTX + irow] = m;                 // log2 domain
        lb [(size_t)js * N_CTX + irow] = lfull;
        mtb[(size_t)js * N_CTX + irow] = mtrue * LN2;       // natural domain
    }
    _Float16* ub = Ub + (((size_t)js * 128 + it) * DIM) * 128 + w * 32 + c31;
    #pragma unroll
    for (int r = 0; r < 16; ++r) {
        int dl = (r & 3) + 8 * (r >> 2) + 4 * hi;
        ub[(size_t)dl * 128]        = (_Float16)U0[r];
        ub[(size_t)(32 + dl) * 128] = (_Float16)U1[r];
        ub[(size_t)(64 + dl) * 128] = (_Float16)U2[r];
        if (96 + dl < DIM) ub[(size_t)(96 + dl) * 128] = (_Float16)U3[r];
    }
}

// ---------------- tail kernels (round-16 configuration) ----------------

// mfull[i] = a[i] + max_js mtb[js][i]; + per-block max Mp[64]
template<int JS>
__global__ void kernel_mf(const float* __restrict__ a, const float* __restrict__ mtb,
                          float* __restrict__ mfull, float* __restrict__ Mp) {
    __shared__ float sm[256];
    int t = threadIdx.x;
    int i = blockIdx.x * 256 + t;
    float mt = -INFINITY;
    #pragma unroll
    for (int js = 0; js < JS; ++js) mt = fmaxf(mt, mtb[(size_t)js * N_CTX + i]);
    float v = a[i] + mt;
    mfull[i] = v;
    sm[t] = v; __syncthreads();
    for (int s = 128; s > 0; s >>= 1) { if (t < s) sm[t] = fmaxf(sm[t], sm[t + s]); __syncthreads(); }
    if (t == 0) Mp[blockIdx.x] = sm[0];
}

// 64 blocks; slice-local scan only: raw h-numerator partials + z partials
__global__ void kernel_h(const float* __restrict__ mfull, const float* __restrict__ Mp,
                         const float* __restrict__ ctx,
                         float* __restrict__ hp, float* __restrict__ zp) {
    __shared__ float smh[8][104];
    __shared__ float smz[8];
    int t = threadIdx.x;
    float M = -INFINITY;
    #pragma unroll 8
    for (int k = 0; k < 64; ++k) M = fmaxf(M, Mp[k]);

    int rr = t >> 5, d32 = t & 31;
    int i0 = blockIdx.x * 256;
    float a0 = 0.f, a1 = 0.f, a2 = 0.f, a3 = 0.f, wz = 0.f;
    for (int g = 0; g < 32; ++g) {
        int row = i0 + g * 8 + rr;
        float bw = __expf(mfull[row] - M);
        const float* cr = ctx + (size_t)row * DIM;
        a0 += bw * cr[d32];
        a1 += bw * cr[d32 + 32];
        a2 += bw * cr[d32 + 64];
        if (d32 < 4) a3 += bw * cr[d32 + 96];
        wz += bw;
    }
    smh[rr][d32]      = a0;
    smh[rr][d32 + 32] = a1;
    smh[rr][d32 + 64] = a2;
    if (d32 < 4) smh[rr][d32 + 96] = a3;
    if (d32 == 0) smz[rr] = wz;
    __syncthreads();
    if (t < DIM) {
        float s = 0.f;
        #pragma unroll
        for (int g = 0; g < 8; ++g) s += smh[g][t];
        hp[blockIdx.x * DIM + t] = s;          // raw numerator
    }
    if (t == 0) {
        float z = 0.f;
        #pragma unroll
        for (int g = 0; g < 8; ++g) z += smz[g];
        zp[blockIdx.x] = z;
    }
}

// ---------------- combine: merge splits + reduce 64 h-partials + G sweep ----
template<int JS>
__global__ __launch_bounds__(256, 4) void combine(
    const _Float16* __restrict__ Ub, const float* __restrict__ mb,
    const float* __restrict__ lb, const float* __restrict__ hp,
    const float* __restrict__ zp, const float* __restrict__ ctx,
    float* __restrict__ G)
{
    __shared__ __align__(16) float ctxL[32][100];
    __shared__ __align__(16) float uaL[32][100];
    __shared__ __align__(16) float hL[100];

    const int b   = blockIdx.x;
    const int tid = threadIdx.x;

    for (int idx = tid; idx < 800; idx += 256) {
        int r = idx / 25, c4 = idx - r * 25;
        *reinterpret_cast<f32x4*>(&ctxL[r][c4 * 4]) =
            *reinterpret_cast<const f32x4*>(ctx + (size_t)(b * 32 + r) * DIM + c4 * 4);
    }
    if (tid < DIM) {
        float s = 0.f, z = 0.f;
        #pragma unroll 8
        for (int bb = 0; bb < 64; ++bb) { s += hp[bb * DIM + tid]; z += zp[bb]; }
        hL[tid] = s / z;
    }
    __syncthreads();

    {
        int i32 = tid & 31, seg = tid >> 5;
        int row = b * 32 + i32;
        int iblk = row >> 7, il = row & 127;
        float mw[JS];
        float M = -INFINITY;
        #pragma unroll
        for (int js = 0; js < JS; ++js) {
            mw[js] = mb[(size_t)js * N_CTX + row];
            M = fmaxf(M, mw[js]);
        }
        float ew[JS];
        float L = 0.f;
        #pragma unroll
        for (int js = 0; js < JS; ++js) {
            ew[js] = EXP2(mw[js] - M);          // mb is log2-domain
            L += lb[(size_t)js * N_CTX + row] * ew[js];
        }
        float invL = 1.f / L;
        for (int d = seg; d < DIM; d += 8) {
            float u = 0.f;
            #pragma unroll
            for (int js = 0; js < JS; ++js)
                u += (float)Ub[(((size_t)js * 128 + iblk) * DIM + d) * 128 + il] * ew[js];
            uaL[i32][d] = u * invL;
        }
    }
    __syncthreads();

    float* gOut = G + (size_t)b * 32 * 400;
    for (int idx = tid; idx < 3200; idx += 256) {
        int r = idx / 100, c4 = idx - r * 100;
        int sel = c4 / 25, d4 = (c4 - sel * 25) * 4;
        f32x4 cv = *reinterpret_cast<const f32x4*>(&ctxL[r][d4]);
        f32x4 out;
        if (sel == 0)      out = cv;
        else if (sel == 1) out = *reinterpret_cast<const f32x4*>(&uaL[r][d4]);
        else if (sel == 2) out = *reinterpret_cast<const f32x4*>(&uaL[r][d4]) * cv;
        else               out = cv * *reinterpret_cast<const f32x4*>(&hL[d4]);
        *reinterpret_cast<f32x4*>(gOut + (size_t)r * 400 + c4 * 4) = out;
    }
}

// ---------------- launcher ----------------
extern "C" void kernel_launch(void* const* d_in, const int* in_sizes, int n_in,
                              void* d_out, int out_size, void* d_ws, size_t ws_size,
                              hipStream_t stream) {
    const float* ctx = (const float*)d_in[0];
    const float* q   = (const float*)d_in[1];
    const float* ker = (const float*)d_in[2];
    float* G = (float*)d_out;

    char* ws = (char*)d_ws;
    unsigned short* qbS   = (unsigned short*)(ws);                 // 1,048,576
    unsigned short* qTS   = (unsigned short*)(ws + 1048576);       // 1,048,576
    unsigned short* cbH   = (unsigned short*)(ws + 2097152);       // 4,194,304
    float*          a     = (float*)(ws + 6291456);                // 65,536
    float*          mfull = (float*)(ws + 6356992);                // 65,536
    float*          hp    = (float*)(ws + 6422528);                // 25,600
    float*          zp    = (float*)(ws + 6448128);                // 256
    float*          Mp    = (float*)(ws + 6448384);                // 256
    const size_t fixed = 6554112;

    int JS = 8;
    if (fixed + 8ull * 3473408ull > ws_size) JS = 4;
    if (fixed + 4ull * 3473408ull > ws_size) JS = 2;

    _Float16* Ub  = (_Float16*)(ws + fixed);
    size_t ubB    = (size_t)JS * 3276800ull;
    float*    mb  = (float*)(ws + fixed + ubB);
    float*    lb  = (float*)(ws + fixed + ubB + (size_t)JS * 65536ull);
    float*    mtb = (float*)(ws + fixed + ubB + (size_t)JS * 131072ull);

    prep_all<<<dim3(128), dim3(256), 0, stream>>>(q, ctx, ker, qbS, qTS, cbH, a);
    attn_main<<<dim3(128, JS), dim3(256), 0, stream>>>(qbS, qTS, cbH, Ub, mb, lb, mtb);

    if (JS == 8) {
        kernel_mf<8><<<dim3(64), dim3(256), 0, stream>>>(a, mtb, mfull, Mp);
        kernel_h<<<dim3(64), dim3(256), 0, stream>>>(mfull, Mp, ctx, hp, zp);
        combine<8><<<dim3(512), dim3(256), 0, stream>>>(Ub, mb, lb, hp, zp, ctx, G);
    } else if (JS == 4) {
        kernel_mf<4><<<dim3(64), dim3(256), 0, stream>>>(a, mtb, mfull, Mp);
        kernel_h<<<dim3(64), dim3(256), 0, stream>>>(mfull, Mp, ctx, hp, zp);
        combine<4><<<dim3(512), dim3(256), 0, stream>>>(Ub, mb, lb, hp, zp, ctx, G);
    } else {
        kernel_mf<2><<<dim3(64), dim3(256), 0, stream>>>(a, mtb, mfull, Mp);
        kernel_h<<<dim3(64), dim3(256), 0, stream>>>(mfull, Mp, ctx, hp, zp);
        combine<2><<<dim3(512), dim3(256), 0, stream>>>(Ub, mb, lb, hp, zp, ctx, G);
    }
}